// Round 5
// baseline (141.338 us; speedup 1.0000x reference)
//
#include <hip/hip_runtime.h>
#include <cstdio>

// B=32, Cin=128, S=8192, H=4, Hc=32, M=64, Cout=128
#define S_LEN 8192
#define NM 64
#define BK 32                // K-step for both MFMA GEMMs

typedef short s8v __attribute__((ext_vector_type(8)));   // 8 bf16 (MFMA A/B frag)
typedef short s4v __attribute__((ext_vector_type(4)));
typedef float f4  __attribute__((ext_vector_type(4)));   // MFMA C/D frag + float4 loads

static __device__ inline unsigned short f2bf(float f) {  // RNE fp32->bf16
    unsigned int u = __builtin_bit_cast(unsigned int, f);
    u = (u + 0x7FFFu + ((u >> 16) & 1u)) >> 16;
    return (unsigned short)u;
}
static __device__ inline float bf2f(unsigned short h) {
    unsigned int u = ((unsigned int)h) << 16;
    return __builtin_bit_cast(float, u);
}

// Swizzled index (ushort units) within a [128 r][32 k] bf16 tile (64 B rows).
// XOR k-bits 3..4 with (r>>1)&3; involution; max 2-way bank aliasing (free, m136).
#define SW32(r, k) (((r) * 32) + ((k) ^ ((((r) >> 1) & 3) << 3)))

// global->LDS DMA, 16B/lane. dst: wave-uniform LDS base (HW adds lane*16);
// src: per-lane global address.
static __device__ __forceinline__ void glds16(const void* g, void* l) {
    __builtin_amdgcn_global_load_lds(
        (const __attribute__((address_space(1))) unsigned int*)g,
        (__attribute__((address_space(3))) unsigned int*)l, 16, 0, 0);
}

// ---------------- table gen (pre-swizzled tile images) ----------------
// T2 image: K1's B^T. (c,kg): c=2m|2m+1 re/im col, value=(c&1)?-sin:cos(2pi m kg/S).
// img[ktile*4096 + SW32(c, kg&31)], ktile=kg>>5 in [0,256).
__global__ __launch_bounds__(256) void gen_t2_img(short* __restrict__ Th,
                                                  short* __restrict__ Tl) {
    int tid = blockIdx.x * 256 + threadIdx.x;     // 1M
    int ktile = tid >> 12;
    int us = tid & 4095;
    int c = us >> 5, kx = us & 31;
    int lk = kx ^ (((c >> 1) & 3) << 3);          // invert swizzle
    int kg = ktile * 32 + lk;
    int m = c >> 1;
    int p = (m * kg) & (S_LEN - 1);
    float ang = (float)p * (6.28318530717958647692f / (float)S_LEN);
    float sn, cs; sincosf(ang, &sn, &cs);
    float v = (c & 1) ? -sn : cs;
    unsigned short h = f2bf(v);
    Th[tid] = (short)h;
    Tl[tid] = (short)f2bf(v - bf2f(h));
}

// T1 image: K3's B^T. (s,k): s=output col, k=2m|2m+1.
// img[(sb*4+kc)*4096 + SW32(s&127, k&31)].
__global__ __launch_bounds__(256) void gen_t1_img(short* __restrict__ Th,
                                                  short* __restrict__ Tl) {
    int tid = blockIdx.x * 256 + threadIdx.x;     // 1M
    int tile = tid >> 12;
    int sb = tile >> 2, kc = tile & 3;
    int us = tid & 4095;
    int ls = us >> 5, kx = us & 31;
    int lk = kx ^ (((ls >> 1) & 3) << 3);
    int s = sb * 128 + ls;
    int k = kc * 32 + lk;
    int m = k >> 1;
    int p = (m * s) & (S_LEN - 1);
    float ang = (float)p * (6.28318530717958647692f / (float)S_LEN);
    float sn, cs; sincosf(ang, &sn, &cs);
    float v = (k & 1) ? -sn : cs;                 // k=1: -sin(0)=0 -> irfft drops Im(DC)
    unsigned short h = f2bf(v);
    Th[tid] = (short)h;
    Tl[tid] = (short)f2bf(v - bf2f(h));
}

// ---------------- K1: P[ks] = x[4096][kslice] * B1[kslice][128], split-bf16 MFMA ----------------
// Double-buffered pipeline; plain P stores (NO atomics).
__global__ __launch_bounds__(256, 2) void dft_fwd_mfma(const float* __restrict__ x,
        const short* __restrict__ T2h, const short* __restrict__ T2l,
        float* __restrict__ P) {
    __shared__ short ah[2][4096], al[2][4096];   // 16 KB each pair-half
    __shared__ short bh[2][4096], bl[2][4096];   // total 64 KB
    const int t = threadIdx.x;
    const int lane = t & 63, wid = t >> 6;
    const int wm = (wid >> 1) * 64, wn = (wid & 1) * 64;
    const int row0 = blockIdx.x * 128;
    const int ks = blockIdx.y, nks = gridDim.y;
    const int chunk = S_LEN / nks, nstep = chunk / BK;
    const int kbase = ks * chunk, ktile0 = kbase / BK;
    f4 acc[4][4];
    #pragma unroll
    for (int i = 0; i < 4; ++i)
        #pragma unroll
        for (int j = 0; j < 4; ++j) acc[i][j] = (f4){0.f, 0.f, 0.f, 0.f};

    f4 av[4];
    const int rA = t >> 3, k4A = (t & 7) * 4;    // per-thread A coords (+32 rows per it)

    #define LOAD_A(kc)  {                                                          \
        _Pragma("unroll")                                                          \
        for (int it = 0; it < 4; ++it)                                             \
            av[it] = __builtin_nontemporal_load((const f4*)&x[                     \
                (size_t)(row0 + rA + it * 32) * S_LEN + kbase + (kc) * BK + k4A]); }

    #define DMA_B(kc, buf)  {                                                      \
        const size_t tb = (size_t)(ktile0 + (kc)) * 8192;                          \
        const int wo = wid * 2048 + lane * 16;                                     \
        glds16((const char*)T2h + tb + wo,        (char*)&bh[buf][0] + wid * 2048);        \
        glds16((const char*)T2h + tb + wo + 1024, (char*)&bh[buf][0] + wid * 2048 + 1024); \
        glds16((const char*)T2l + tb + wo,        (char*)&bl[buf][0] + wid * 2048);        \
        glds16((const char*)T2l + tb + wo + 1024, (char*)&bl[buf][0] + wid * 2048 + 1024); }

    #define CONV_A(buf)  {                                                         \
        _Pragma("unroll")                                                          \
        for (int it = 0; it < 4; ++it) {                                           \
            s4v hv, lv;                                                            \
            _Pragma("unroll")                                                      \
            for (int e = 0; e < 4; ++e) {                                          \
                unsigned short h = f2bf(av[it][e]);                                \
                hv[e] = (short)h; lv[e] = (short)f2bf(av[it][e] - bf2f(h));        \
            }                                                                      \
            int us = SW32(rA + it * 32, k4A);                                      \
            *(s4v*)&ah[buf][us] = hv;                                              \
            *(s4v*)&al[buf][us] = lv;                                              \
        } }

    #define MMAC(buf)  {                                                           \
        const int kk = (lane >> 4) * 8, rl = lane & 15;                            \
        s8v Ah[4], Al[4], Bh[4], Bl[4];                                            \
        _Pragma("unroll")                                                          \
        for (int mf = 0; mf < 4; ++mf) {                                           \
            int us = SW32(wm + mf * 16 + rl, kk);                                  \
            Ah[mf] = *(const s8v*)&ah[buf][us];                                    \
            Al[mf] = *(const s8v*)&al[buf][us];                                    \
        }                                                                          \
        _Pragma("unroll")                                                          \
        for (int nf = 0; nf < 4; ++nf) {                                           \
            int us = SW32(wn + nf * 16 + rl, kk);                                  \
            Bh[nf] = *(const s8v*)&bh[buf][us];                                    \
            Bl[nf] = *(const s8v*)&bl[buf][us];                                    \
        }                                                                          \
        _Pragma("unroll")                                                          \
        for (int mf = 0; mf < 4; ++mf)                                             \
            _Pragma("unroll")                                                      \
            for (int nf = 0; nf < 4; ++nf)                                         \
                acc[mf][nf] = __builtin_amdgcn_mfma_f32_16x16x32_bf16(Ah[mf], Bh[nf], acc[mf][nf], 0, 0, 0); \
        _Pragma("unroll")                                                          \
        for (int mf = 0; mf < 4; ++mf)                                             \
            _Pragma("unroll")                                                      \
            for (int nf = 0; nf < 4; ++nf)                                         \
                acc[mf][nf] = __builtin_amdgcn_mfma_f32_16x16x32_bf16(Al[mf], Bh[nf], acc[mf][nf], 0, 0, 0); \
        _Pragma("unroll")                                                          \
        for (int mf = 0; mf < 4; ++mf)                                             \
            _Pragma("unroll")                                                      \
            for (int nf = 0; nf < 4; ++nf)                                         \
                acc[mf][nf] = __builtin_amdgcn_mfma_f32_16x16x32_bf16(Ah[mf], Bl[nf], acc[mf][nf], 0, 0, 0); }

    // prologue: stage step 0
    LOAD_A(0); DMA_B(0, 0); CONV_A(0);
    __syncthreads();
    for (int kc = 0; kc < nstep; ++kc) {
        const int cur = kc & 1, nxt = cur ^ 1;
        const bool more = (kc + 1 < nstep);
        if (more) { LOAD_A(kc + 1); DMA_B(kc + 1, nxt); }   // prefetch in flight...
        MMAC(cur);                                          // ...under MFMA
        if (more) CONV_A(nxt);                              // waits vmcnt(4): A only
        __syncthreads();                                    // drains B-DMA + ds
    }
    // epilogue: plain stores of this ks-partial
    float* Pks = P + (size_t)ks * 4096 * 128;
    #pragma unroll
    for (int mf = 0; mf < 4; ++mf) {
        int rb = row0 + wm + mf * 16 + (lane >> 4) * 4;
        #pragma unroll
        for (int nf = 0; nf < 4; ++nf) {
            int c = wn + nf * 16 + (lane & 15);
            #pragma unroll
            for (int r = 0; r < 4; ++r)
                Pks[(size_t)(rb + r) * 128 + c] = acc[mf][nf][r];
        }
    }
}

// ---------------- ksum: X = sum_ks P[ks], coalesced ----------------
__global__ __launch_bounds__(256) void ksum(const float* __restrict__ P,
                                            float* __restrict__ X, int nks) {
    int i = (blockIdx.x * 256 + threadIdx.x) * 4;
    f4 s = (f4){0.f, 0.f, 0.f, 0.f};
    for (int ks = 0; ks < nks; ++ks)
        s += *(const f4*)&P[(size_t)ks * 524288 + i];
    *(f4*)&X[i] = s;
}

// ---------------- K2: mode contraction -> C2 image (pre-swizzled bf16 hi/lo) ----------------
__global__ __launch_bounds__(256) void mode_contract(const float* __restrict__ X,
        const float* __restrict__ w_real, const float* __restrict__ w_imag,
        short* __restrict__ C2h, short* __restrict__ C2l) {
    __shared__ float xr[32][128], xi[32][128];
    __shared__ float wr[128][32], wi[128][32];
    const int m = blockIdx.x, h = blockIdx.y, t = threadIdx.x;
    #pragma unroll
    for (int it = 0; it < 16; ++it) {
        int li = t + it * 256;       // 0..4095
        int b = li >> 7, i = li & 127;
        const float2 v = *(const float2*)&X[(size_t)(b * 128 + i) * 128 + 2 * m];
        xr[b][i] = v.x; xi[b][i] = v.y;
        int i2 = li >> 5, o = li & 31;
        size_t off = ((size_t)((h * 128 + i2) * 32 + o)) * NM + m;
        wr[i2][o] = w_real[off];
        wi[i2][o] = w_imag[off];
    }
    __syncthreads();
    const int o = t & 31;
    const int b0 = (t >> 5) * 4;
    float re[4] = {0.f, 0.f, 0.f, 0.f}, im[4] = {0.f, 0.f, 0.f, 0.f};
    for (int i = 0; i < 128; ++i) {
        float wrv = wr[i][o], wiv = wi[i][o];
        #pragma unroll
        for (int j = 0; j < 4; ++j) {
            float a = xr[b0 + j][i], c = xi[b0 + j][i];
            re[j] += a * wrv - c * wiv;
            im[j] += a * wiv + c * wrv;
        }
    }
    const float alpha = (m == 0) ? (1.0f / (float)S_LEN) : (2.0f / (float)S_LEN);
    const int kc = m >> 4;
    const int lk = (2 * m) & 31;
    #pragma unroll
    for (int j = 0; j < 4; ++j) {
        int row = (b0 + j) * 128 + h * 32 + o;
        float vr = alpha * re[j], vi = alpha * im[j];
        unsigned short hr = f2bf(vr), hi_ = f2bf(vi);
        float lr = vr - bf2f(hr), li_ = vi - bf2f(hi_);
        int rb = row >> 7, lr_ = row & 127;
        size_t ui = ((size_t)(rb * 4 + kc) * 4096 + SW32(lr_, lk)) >> 1;   // uint index
        ((unsigned int*)C2h)[ui] = ((unsigned int)hi_ << 16) | hr;
        ((unsigned int*)C2l)[ui] = ((unsigned int)f2bf(li_) << 16) | f2bf(lr);
    }
}

// ---------------- K3: y = C2[4096][128] * Basis[128][8192], dbuf DMA pipeline ----------------
__global__ __launch_bounds__(256, 2) void idft_mfma(const short* __restrict__ C2h,
        const short* __restrict__ C2l, const short* __restrict__ T1h,
        const short* __restrict__ T1l, float* __restrict__ y) {
    __shared__ short ah[2][4096], al[2][4096];
    __shared__ short bh[2][4096], bl[2][4096];
    const int t = threadIdx.x;
    const int lane = t & 63, wid = t >> 6;
    const int wm = (wid >> 1) * 64, wn = (wid & 1) * 64;
    const int sb = blockIdx.x;                    // col block (s), 0..63
    const int rb = blockIdx.y;                    // row block, 0..31
    f4 acc[4][4];
    #pragma unroll
    for (int i = 0; i < 4; ++i)
        #pragma unroll
        for (int j = 0; j < 4; ++j) acc[i][j] = (f4){0.f, 0.f, 0.f, 0.f};

    #define DMA3(kc, buf)  {                                                       \
        const size_t ta = (size_t)(rb * 4 + (kc)) * 8192;                          \
        const size_t tb = (size_t)(sb * 4 + (kc)) * 8192;                          \
        const int wo = wid * 2048 + lane * 16;                                     \
        glds16((const char*)C2h + ta + wo,        (char*)&ah[buf][0] + wid * 2048);        \
        glds16((const char*)C2h + ta + wo + 1024, (char*)&ah[buf][0] + wid * 2048 + 1024); \
        glds16((const char*)C2l + ta + wo,        (char*)&al[buf][0] + wid * 2048);        \
        glds16((const char*)C2l + ta + wo + 1024, (char*)&al[buf][0] + wid * 2048 + 1024); \
        glds16((const char*)T1h + tb + wo,        (char*)&bh[buf][0] + wid * 2048);        \
        glds16((const char*)T1h + tb + wo + 1024, (char*)&bh[buf][0] + wid * 2048 + 1024); \
        glds16((const char*)T1l + tb + wo,        (char*)&bl[buf][0] + wid * 2048);        \
        glds16((const char*)T1l + tb + wo + 1024, (char*)&bl[buf][0] + wid * 2048 + 1024); }

    DMA3(0, 0);
    __syncthreads();
    #pragma unroll
    for (int kc = 0; kc < 4; ++kc) {
        const int cur = kc & 1;
        if (kc < 3) DMA3(kc + 1, cur ^ 1);
        {
            const int kk = (lane >> 4) * 8, rl = lane & 15;
            s8v Ah[4], Al[4], Bh[4], Bl[4];
            #pragma unroll
            for (int mf = 0; mf < 4; ++mf) {
                int us = SW32(wm + mf * 16 + rl, kk);
                Ah[mf] = *(const s8v*)&ah[cur][us];
                Al[mf] = *(const s8v*)&al[cur][us];
            }
            #pragma unroll
            for (int nf = 0; nf < 4; ++nf) {
                int us = SW32(wn + nf * 16 + rl, kk);
                Bh[nf] = *(const s8v*)&bh[cur][us];
                Bl[nf] = *(const s8v*)&bl[cur][us];
            }
            #pragma unroll
            for (int mf = 0; mf < 4; ++mf)
                #pragma unroll
                for (int nf = 0; nf < 4; ++nf)
                    acc[mf][nf] = __builtin_amdgcn_mfma_f32_16x16x32_bf16(Ah[mf], Bh[nf], acc[mf][nf], 0, 0, 0);
            #pragma unroll
            for (int mf = 0; mf < 4; ++mf)
                #pragma unroll
                for (int nf = 0; nf < 4; ++nf)
                    acc[mf][nf] = __builtin_amdgcn_mfma_f32_16x16x32_bf16(Al[mf], Bh[nf], acc[mf][nf], 0, 0, 0);
            #pragma unroll
            for (int mf = 0; mf < 4; ++mf)
                #pragma unroll
                for (int nf = 0; nf < 4; ++nf)
                    acc[mf][nf] = __builtin_amdgcn_mfma_f32_16x16x32_bf16(Ah[mf], Bl[nf], acc[mf][nf], 0, 0, 0);
        }
        __syncthreads();
    }
    #pragma unroll
    for (int mf = 0; mf < 4; ++mf) {
        int rr = rb * 128 + wm + mf * 16 + (lane >> 4) * 4;
        #pragma unroll
        for (int nf = 0; nf < 4; ++nf) {
            int c = sb * 128 + wn + nf * 16 + (lane & 15);
            #pragma unroll
            for (int r = 0; r < 4; ++r)
                __builtin_nontemporal_store(acc[mf][nf][r], &y[(size_t)(rr + r) * S_LEN + c]);
        }
    }
}

extern "C" void kernel_launch(void* const* d_in, const int* in_sizes, int n_in,
                              void* d_out, int out_size, void* d_ws, size_t ws_size,
                              hipStream_t stream) {
    const float* x      = (const float*)d_in[0];
    const float* w_real = (const float*)d_in[1];
    const float* w_imag = (const float*)d_in[2];
    float* y = (float*)d_out;

    const size_t TBL = (size_t)S_LEN * 128;       // 1M ushort per table half
    char* w0 = (char*)d_ws;
    short* T1h = (short*)w0;                      // 2MB each half
    short* T1l = T1h + TBL;
    short* T2h = T1l + TBL;
    short* T2l = T2h + TBL;
    float* X   = (float*)(T2l + TBL);             // 2MB
    short* C2h = (short*)(X + (size_t)4096 * 128);// 2MB each half
    short* C2l = C2h + (size_t)4096 * 128;
    float* P   = (float*)(C2l + (size_t)4096 * 128);
    const size_t BASE = (size_t)((char*)P - w0);  // 14MB

    int nks = 16;                                  // P = nks * 2MB
    while (nks > 1 && BASE + (size_t)nks * 4096 * 128 * sizeof(float) > ws_size)
        nks >>= 1;
    if (BASE + (size_t)nks * 4096 * 128 * sizeof(float) > ws_size) {
        fprintf(stderr, "kernel_launch: ws too small (%zu)\n", ws_size);
        return;
    }

    gen_t1_img<<<(S_LEN * 128) / 256, 256, 0, stream>>>(T1h, T1l);
    gen_t2_img<<<(S_LEN * 128) / 256, 256, 0, stream>>>(T2h, T2l);
    dft_fwd_mfma<<<dim3(4096 / 128, nks), 256, 0, stream>>>(x, T2h, T2l, P);
    ksum<<<512, 256, 0, stream>>>(P, X, nks);
    mode_contract<<<dim3(NM, 4), 256, 0, stream>>>(X, w_real, w_imag, C2h, C2l);
    idft_mfma<<<dim3(S_LEN / 128, 4096 / 128), 256, 0, stream>>>(C2h, C2l, T1h, T1l, y);
}

// Round 6
// 127.425 us; speedup vs baseline: 1.1092x; 1.1092x over previous
//
#include <hip/hip_runtime.h>
#include <cstdio>

// B=32, Cin=128, S=8192, H=4, Hc=32, M=64, Cout=128
#define S_LEN 8192
#define NM 64

typedef short s8v __attribute__((ext_vector_type(8)));   // 8 bf16 (MFMA A/B frag)
typedef short s4v __attribute__((ext_vector_type(4)));
typedef float f4  __attribute__((ext_vector_type(4)));   // MFMA C/D frag + float4 loads

static __device__ inline unsigned short f2bf(float f) {  // RNE fp32->bf16
    unsigned int u = __builtin_bit_cast(unsigned int, f);
    u = (u + 0x7FFFu + ((u >> 16) & 1u)) >> 16;
    return (unsigned short)u;
}
static __device__ inline float bf2f(unsigned short h) {
    unsigned int u = ((unsigned int)h) << 16;
    return __builtin_bit_cast(float, u);
}

// K3-side swizzle (unchanged): [128 r][32 k] tile, XOR k-bits 3..4 with (r>>1)&3
#define SW32(r, k) (((r) * 32) + ((k) ^ ((((r) >> 1) & 3) << 3)))

static __device__ __forceinline__ void glds16(const void* g, void* l) {
    __builtin_amdgcn_global_load_lds(
        (const __attribute__((address_space(1))) unsigned int*)g,
        (__attribute__((address_space(3))) unsigned int*)l, 16, 0, 0);
}

// ---------------- table gen ----------------
// T1 image (K3's B^T, UNCHANGED layout): (s,k) k=2m|2m+1; img[(sb*4+kc)*4096 + SW32(s&127,k&31)]
__global__ __launch_bounds__(256) void gen_t1_img(short* __restrict__ Th,
                                                  short* __restrict__ Tl) {
    int tid = blockIdx.x * 256 + threadIdx.x;     // 1M
    int tile = tid >> 12;
    int sb = tile >> 2, kc = tile & 3;
    int us = tid & 4095;
    int ls = us >> 5, kx = us & 31;
    int lk = kx ^ (((ls >> 1) & 3) << 3);
    int s = sb * 128 + ls;
    int k = kc * 32 + lk;
    int m = k >> 1;
    int p = (m * s) & (S_LEN - 1);
    float ang = (float)p * (6.28318530717958647692f / (float)S_LEN);
    float sn, cs; sincosf(ang, &sn, &cs);
    float v = (k & 1) ? -sn : cs;                 // k=1: -sin(0)=0 -> irfft drops Im(DC)
    unsigned short h = f2bf(v);
    Th[tid] = (short)h;
    Tl[tid] = (short)f2bf(v - bf2f(h));
}

// T2 image (K1's B^T, NEW tiling): tiles of [64 c][64 k] shorts (8 KB), swizzle
// k' = k ^ ((c&7)<<3). Tile index = (kstep64 * 2 + colhalf), kstep64 in [0,128).
// col = colhalf*64 + c; value = (col&1) ? -sin(2pi m kg/S) : cos, m=col>>1, kg=kstep64*64+k.
__global__ __launch_bounds__(256) void gen_t2_img(short* __restrict__ Th,
                                                  short* __restrict__ Tl) {
    int tid = blockIdx.x * 256 + threadIdx.x;     // 1M
    int tile = tid >> 12;
    int t64 = tile >> 1, ch = tile & 1;
    int us = tid & 4095;
    int c = us >> 6, kx = us & 63;
    int k = kx ^ ((c & 7) << 3);                  // invert swizzle
    int col = ch * 64 + c;
    int m = col >> 1;
    int kg = t64 * 64 + k;
    int p = (m * kg) & (S_LEN - 1);
    float ang = (float)p * (6.28318530717958647692f / (float)S_LEN);
    float sn, cs; sincosf(ang, &sn, &cs);
    float v = (col & 1) ? -sn : cs;
    unsigned short h = f2bf(v);
    Th[tid] = (short)h;
    Tl[tid] = (short)f2bf(v - bf2f(h));
}

// ---------------- K1: P[ks] = x[4096][kchunk] * B1[kchunk][128], split-bf16 MFMA ----------------
// BM=128, BK=64. A fetched as 4 rows x 256B-contiguous per wave-instr (anti channel-camping),
// step order rotated per rowblock. B via glds from pre-swizzled images.
__global__ __launch_bounds__(256, 2) void dft_fwd_mfma(const float* __restrict__ x,
        const short* __restrict__ T2h, const short* __restrict__ T2l,
        float* __restrict__ P) {
    __shared__ short ah[128 * 64], al[128 * 64];      // 16 KB each
    __shared__ short bh[2][64 * 64], bl[2][64 * 64];  // 8 KB per buf per comp (32 KB)
    const int t = threadIdx.x;
    const int lane = t & 63, wid = t >> 6;
    const int wr = wid >> 1, wc = wid & 1;
    const int rblk = blockIdx.x;
    const int row0 = rblk * 128;
    const int ks = blockIdx.y, nks = gridDim.y;
    const int chunk = S_LEN / nks, nstep = chunk / 64;
    const int kbase = ks * chunk;
    const int tbase = (kbase / 64) * 2;               // image tile base (2 col-halves per kstep)

    f4 acc[2][4][2];
    #pragma unroll
    for (int p = 0; p < 2; ++p)
        #pragma unroll
        for (int i = 0; i < 4; ++i)
            #pragma unroll
            for (int j = 0; j < 2; ++j) acc[p][i][j] = (f4){0.f, 0.f, 0.f, 0.f};

    const int rA0 = (wid << 2) + (lane >> 4);         // row within tile (+ i*16)
    const int kfA = (lane & 15) << 2;                 // float offset within 64-float window
    const int rl = lane & 15, kq = lane >> 4;

    for (int kc = 0; kc < nstep; ++kc) {
        const int kcr = (kc + rblk) & (nstep - 1);    // rotated step (accumulation commutes)
        const int kwin = kbase + kcr * 64;
        // ---- A loads: 8 x float4; each wave-instr = 4 rows x 256 B contiguous
        f4 av[8];
        #pragma unroll
        for (int i = 0; i < 8; ++i)
            av[i] = *(const f4*)&x[(size_t)(row0 + rA0 + i * 16) * S_LEN + kwin + kfA];
        __builtin_amdgcn_sched_barrier(0);
        // ---- B DMA: both col-half phases, from pre-swizzled images
        {
            const int wo = wid * 2048 + lane * 16;    // bytes
            #pragma unroll
            for (int ph = 0; ph < 2; ++ph) {
                const size_t tb = (size_t)(tbase + kcr * 2 + ph) * 8192;
                glds16((const char*)T2h + tb + wo,        (char*)&bh[ph][0] + wid * 2048);
                glds16((const char*)T2h + tb + wo + 1024, (char*)&bh[ph][0] + wid * 2048 + 1024);
                glds16((const char*)T2l + tb + wo,        (char*)&bl[ph][0] + wid * 2048);
                glds16((const char*)T2l + tb + wo + 1024, (char*)&bl[ph][0] + wid * 2048 + 1024);
            }
        }
        __builtin_amdgcn_sched_barrier(0);
        // ---- convert A -> bf16 hi/lo, swizzled ds_write (waits only A loads; B-DMA in flight)
        #pragma unroll
        for (int i = 0; i < 8; ++i) {
            const int r = rA0 + i * 16;
            s4v hv, lv;
            #pragma unroll
            for (int e = 0; e < 4; ++e) {
                unsigned short h = f2bf(av[i][e]);
                hv[e] = (short)h; lv[e] = (short)f2bf(av[i][e] - bf2f(h));
            }
            const int us = r * 64 + (kfA ^ ((r & 7) << 3));
            *(s4v*)&ah[us] = hv;
            *(s4v*)&al[us] = lv;
        }
        __syncthreads();                               // A-tile + both B bufs ready
        // ---- A fragments (both 32-k slices, all 4 mf)
        s8v Afh[2][4], Afl[2][4];
        #pragma unroll
        for (int ksl = 0; ksl < 2; ++ksl)
            #pragma unroll
            for (int mf = 0; mf < 4; ++mf) {
                const int r = wr * 64 + mf * 16 + rl;
                const int b = ksl * 4 + kq;
                const int us = r * 64 + ((b ^ (r & 7)) << 3);
                Afh[ksl][mf] = *(const s8v*)&ah[us];
                Afl[ksl][mf] = *(const s8v*)&al[us];
            }
        // ---- MFMA: two col-phases x two k-slices; 8-way acc interleave per pass
        #pragma unroll
        for (int ph = 0; ph < 2; ++ph) {
            #pragma unroll
            for (int ksl = 0; ksl < 2; ++ksl) {
                s8v Bh_[2], Bl_[2];
                #pragma unroll
                for (int nf = 0; nf < 2; ++nf) {
                    const int c = wc * 32 + nf * 16 + rl;
                    const int b = ksl * 4 + kq;
                    const int us = c * 64 + ((b ^ (c & 7)) << 3);
                    Bh_[nf] = *(const s8v*)&bh[ph][us];
                    Bl_[nf] = *(const s8v*)&bl[ph][us];
                }
                #pragma unroll
                for (int mf = 0; mf < 4; ++mf)
                    #pragma unroll
                    for (int nf = 0; nf < 2; ++nf)
                        acc[ph][mf][nf] = __builtin_amdgcn_mfma_f32_16x16x32_bf16(
                            Afh[ksl][mf], Bh_[nf], acc[ph][mf][nf], 0, 0, 0);
                #pragma unroll
                for (int mf = 0; mf < 4; ++mf)
                    #pragma unroll
                    for (int nf = 0; nf < 2; ++nf)
                        acc[ph][mf][nf] = __builtin_amdgcn_mfma_f32_16x16x32_bf16(
                            Afl[ksl][mf], Bh_[nf], acc[ph][mf][nf], 0, 0, 0);
                #pragma unroll
                for (int mf = 0; mf < 4; ++mf)
                    #pragma unroll
                    for (int nf = 0; nf < 2; ++nf)
                        acc[ph][mf][nf] = __builtin_amdgcn_mfma_f32_16x16x32_bf16(
                            Afh[ksl][mf], Bl_[nf], acc[ph][mf][nf], 0, 0, 0);
            }
        }
        __syncthreads();                               // release A-tile + B bufs
    }
    // ---- epilogue: plain stores of this ks-partial
    float* Pks = P + (size_t)ks * 4096 * 128;
    #pragma unroll
    for (int ph = 0; ph < 2; ++ph)
        #pragma unroll
        for (int mf = 0; mf < 4; ++mf) {
            const int rb = row0 + wr * 64 + mf * 16 + kq * 4;
            #pragma unroll
            for (int nf = 0; nf < 2; ++nf) {
                const int c = ph * 64 + wc * 32 + nf * 16 + rl;
                #pragma unroll
                for (int r = 0; r < 4; ++r)
                    Pks[(size_t)(rb + r) * 128 + c] = acc[ph][mf][nf][r];
            }
        }
}

// ---------------- ksum: X = sum_ks P[ks], coalesced ----------------
__global__ __launch_bounds__(256) void ksum(const float* __restrict__ P,
                                            float* __restrict__ X, int nks) {
    int i = (blockIdx.x * 256 + threadIdx.x) * 4;
    f4 s = (f4){0.f, 0.f, 0.f, 0.f};
    for (int ks = 0; ks < nks; ++ks)
        s += *(const f4*)&P[(size_t)ks * 524288 + i];
    *(f4*)&X[i] = s;
}

// ---------------- K2: mode contraction -> C2 image (pre-swizzled bf16 hi/lo) ----------------
__global__ __launch_bounds__(256) void mode_contract(const float* __restrict__ X,
        const float* __restrict__ w_real, const float* __restrict__ w_imag,
        short* __restrict__ C2h, short* __restrict__ C2l) {
    __shared__ float xr[32][128], xi[32][128];
    __shared__ float wr[128][32], wi[128][32];
    const int m = blockIdx.x, h = blockIdx.y, t = threadIdx.x;
    #pragma unroll
    for (int it = 0; it < 16; ++it) {
        int li = t + it * 256;       // 0..4095
        int b = li >> 7, i = li & 127;
        const float2 v = *(const float2*)&X[(size_t)(b * 128 + i) * 128 + 2 * m];
        xr[b][i] = v.x; xi[b][i] = v.y;
        int i2 = li >> 5, o = li & 31;
        size_t off = ((size_t)((h * 128 + i2) * 32 + o)) * NM + m;
        wr[i2][o] = w_real[off];
        wi[i2][o] = w_imag[off];
    }
    __syncthreads();
    const int o = t & 31;
    const int b0 = (t >> 5) * 4;
    float re[4] = {0.f, 0.f, 0.f, 0.f}, im[4] = {0.f, 0.f, 0.f, 0.f};
    for (int i = 0; i < 128; ++i) {
        float wrv = wr[i][o], wiv = wi[i][o];
        #pragma unroll
        for (int j = 0; j < 4; ++j) {
            float a = xr[b0 + j][i], c = xi[b0 + j][i];
            re[j] += a * wrv - c * wiv;
            im[j] += a * wiv + c * wrv;
        }
    }
    const float alpha = (m == 0) ? (1.0f / (float)S_LEN) : (2.0f / (float)S_LEN);
    const int kc = m >> 4;
    const int lk = (2 * m) & 31;
    #pragma unroll
    for (int j = 0; j < 4; ++j) {
        int row = (b0 + j) * 128 + h * 32 + o;
        float vr = alpha * re[j], vi = alpha * im[j];
        unsigned short hr = f2bf(vr), hi_ = f2bf(vi);
        float lr = vr - bf2f(hr), li_ = vi - bf2f(hi_);
        int rb = row >> 7, lr_ = row & 127;
        size_t ui = ((size_t)(rb * 4 + kc) * 4096 + SW32(lr_, lk)) >> 1;   // uint index
        ((unsigned int*)C2h)[ui] = ((unsigned int)hi_ << 16) | hr;
        ((unsigned int*)C2l)[ui] = ((unsigned int)f2bf(li_) << 16) | f2bf(lr);
    }
}

// ---------------- K3: y = C2[4096][128] * Basis[128][8192], dbuf DMA pipeline ----------------
__global__ __launch_bounds__(256, 2) void idft_mfma(const short* __restrict__ C2h,
        const short* __restrict__ C2l, const short* __restrict__ T1h,
        const short* __restrict__ T1l, float* __restrict__ y) {
    __shared__ short ah[2][4096], al[2][4096];
    __shared__ short bh[2][4096], bl[2][4096];
    const int t = threadIdx.x;
    const int lane = t & 63, wid = t >> 6;
    const int wm = (wid >> 1) * 64, wn = (wid & 1) * 64;
    const int sb = blockIdx.x;                    // col block (s), 0..63
    const int rb = blockIdx.y;                    // row block, 0..31
    f4 acc[4][4];
    #pragma unroll
    for (int i = 0; i < 4; ++i)
        #pragma unroll
        for (int j = 0; j < 4; ++j) acc[i][j] = (f4){0.f, 0.f, 0.f, 0.f};

    #define DMA3(kc, buf)  {                                                       \
        const size_t ta = (size_t)(rb * 4 + (kc)) * 8192;                          \
        const size_t tb = (size_t)(sb * 4 + (kc)) * 8192;                          \
        const int wo = wid * 2048 + lane * 16;                                     \
        glds16((const char*)C2h + ta + wo,        (char*)&ah[buf][0] + wid * 2048);        \
        glds16((const char*)C2h + ta + wo + 1024, (char*)&ah[buf][0] + wid * 2048 + 1024); \
        glds16((const char*)C2l + ta + wo,        (char*)&al[buf][0] + wid * 2048);        \
        glds16((const char*)C2l + ta + wo + 1024, (char*)&al[buf][0] + wid * 2048 + 1024); \
        glds16((const char*)T1h + tb + wo,        (char*)&bh[buf][0] + wid * 2048);        \
        glds16((const char*)T1h + tb + wo + 1024, (char*)&bh[buf][0] + wid * 2048 + 1024); \
        glds16((const char*)T1l + tb + wo,        (char*)&bl[buf][0] + wid * 2048);        \
        glds16((const char*)T1l + tb + wo + 1024, (char*)&bl[buf][0] + wid * 2048 + 1024); }

    DMA3(0, 0);
    __syncthreads();
    #pragma unroll
    for (int kc = 0; kc < 4; ++kc) {
        const int cur = kc & 1;
        if (kc < 3) DMA3(kc + 1, cur ^ 1);
        {
            const int kk = (lane >> 4) * 8, rl = lane & 15;
            s8v Ah[4], Al[4], Bh[4], Bl[4];
            #pragma unroll
            for (int mf = 0; mf < 4; ++mf) {
                int us = SW32(wm + mf * 16 + rl, kk);
                Ah[mf] = *(const s8v*)&ah[cur][us];
                Al[mf] = *(const s8v*)&al[cur][us];
            }
            #pragma unroll
            for (int nf = 0; nf < 4; ++nf) {
                int us = SW32(wn + nf * 16 + rl, kk);
                Bh[nf] = *(const s8v*)&bh[cur][us];
                Bl[nf] = *(const s8v*)&bl[cur][us];
            }
            #pragma unroll
            for (int mf = 0; mf < 4; ++mf)
                #pragma unroll
                for (int nf = 0; nf < 4; ++nf)
                    acc[mf][nf] = __builtin_amdgcn_mfma_f32_16x16x32_bf16(Ah[mf], Bh[nf], acc[mf][nf], 0, 0, 0);
            #pragma unroll
            for (int mf = 0; mf < 4; ++mf)
                #pragma unroll
                for (int nf = 0; nf < 4; ++nf)
                    acc[mf][nf] = __builtin_amdgcn_mfma_f32_16x16x32_bf16(Al[mf], Bh[nf], acc[mf][nf], 0, 0, 0);
            #pragma unroll
            for (int mf = 0; mf < 4; ++mf)
                #pragma unroll
                for (int nf = 0; nf < 4; ++nf)
                    acc[mf][nf] = __builtin_amdgcn_mfma_f32_16x16x32_bf16(Ah[mf], Bl[nf], acc[mf][nf], 0, 0, 0);
        }
        __syncthreads();
    }
    #pragma unroll
    for (int mf = 0; mf < 4; ++mf) {
        int rr = rb * 128 + wm + mf * 16 + (lane >> 4) * 4;
        #pragma unroll
        for (int nf = 0; nf < 4; ++nf) {
            int c = sb * 128 + wn + nf * 16 + (lane & 15);
            #pragma unroll
            for (int r = 0; r < 4; ++r)
                __builtin_nontemporal_store(acc[mf][nf][r], &y[(size_t)(rr + r) * S_LEN + c]);
        }
    }
}

extern "C" void kernel_launch(void* const* d_in, const int* in_sizes, int n_in,
                              void* d_out, int out_size, void* d_ws, size_t ws_size,
                              hipStream_t stream) {
    const float* x      = (const float*)d_in[0];
    const float* w_real = (const float*)d_in[1];
    const float* w_imag = (const float*)d_in[2];
    float* y = (float*)d_out;

    const size_t TBL = (size_t)S_LEN * 128;       // 1M shorts per table half
    char* w0 = (char*)d_ws;
    short* T1h = (short*)w0;                      // 2MB each half
    short* T1l = T1h + TBL;
    short* T2h = T1l + TBL;
    short* T2l = T2h + TBL;
    float* X   = (float*)(T2l + TBL);             // 2MB
    short* C2h = (short*)(X + (size_t)4096 * 128);// 2MB each half
    short* C2l = C2h + (size_t)4096 * 128;
    float* P   = (float*)(C2l + (size_t)4096 * 128);
    const size_t BASE = (size_t)((char*)P - w0);  // 14MB

    int nks = 16;                                  // P = nks * 2MB
    while (nks > 1 && BASE + (size_t)nks * 4096 * 128 * sizeof(float) > ws_size)
        nks >>= 1;
    if (BASE + (size_t)nks * 4096 * 128 * sizeof(float) > ws_size) {
        fprintf(stderr, "kernel_launch: ws too small (%zu)\n", ws_size);
        return;
    }

    gen_t1_img<<<(S_LEN * 128) / 256, 256, 0, stream>>>(T1h, T1l);
    gen_t2_img<<<(S_LEN * 128) / 256, 256, 0, stream>>>(T2h, T2l);
    dft_fwd_mfma<<<dim3(4096 / 128, nks), 256, 0, stream>>>(x, T2h, T2l, P);
    ksum<<<512, 256, 0, stream>>>(P, X, nks);
    mode_contract<<<dim3(NM, 4), 256, 0, stream>>>(X, w_real, w_imag, C2h, C2l);
    idft_mfma<<<dim3(S_LEN / 128, 4096 / 128), 256, 0, stream>>>(C2h, C2l, T1h, T1l, y);
}